// Round 1
// baseline (630.236 us; speedup 1.0000x reference)
//
#include <hip/hip_runtime.h>
#include <stdint.h>

namespace {

constexpr int B = 8;
constexpr int H = 1024;
constexpr int W = 1024;
constexpr int TOPK = 4096;
constexpr int CAND_CAP = 131072;  // per batch
constexpr int SEL_CAP = 16384;    // per batch
constexpr int LIST_CAP = 320;     // per 64x64 tile
constexpr int HIST_N = 32768;     // 17-bit key prefix = score_bits>>15

// fused-NMS tile: 64x64 interior, radius-12 staged halo.
// Validity chain (3 fused stages): M0 mask valid rows [2,89]/cols [2,86);
// M1 (cumulative after iter1) valid rows [4,87]/cols [4,84); final emission
// valid rows [6,85]/cols [6,82) => interior rows/cols 12..75 fully covered.
constexpr int RROWS = 92;   // staged score rows
constexpr int NG = 22;      // float4 col-groups (88 cols)
constexpr int STR = 88;     // score row stride (floats)
constexpr int MW4 = 4;      // bitpacked mask words per row (96+ bits; word 3 = zero pad)
constexpr int NSTRIP = 11;  // 11 strips x 8 output rows = rows 2..89
constexpr int NUNIT = NG * NSTRIP;  // 242 <= 256

constexpr int RK_CH = 1024;  // rank kernel: keys staged in LDS per chunk

// workspace layout (bytes)
constexpr size_t OFF_CNT   = 0;                                    // 4 KiB
constexpr size_t OFF_GHIST = 4096;                                 // B*HIST_N*4 = 1 MiB
constexpr size_t OFF_RANK  = OFF_GHIST + (size_t)B * HIST_N * 4;   // (region unused now)
constexpr size_t OFF_SEL   = OFF_RANK + (size_t)B * SEL_CAP * 4;
constexpr size_t OFF_TOPK  = OFF_SEL + (size_t)B * SEL_CAP * 8;
constexpr size_t OFF_CAND  = OFF_TOPK + (size_t)B * TOPK * 8;
constexpr size_t MEMSET_BYTES = OFF_RANK;  // cnt + ghist only

__device__ __forceinline__ float max5(float a, float b, float c, float d, float e) {
  return fmaxf(fmaxf(fmaxf(a, b), fmaxf(c, d)), e);
}
__device__ __forceinline__ float4 ld4(const float* p) {
  return *reinterpret_cast<const float4*>(p);
}

// One unit: col-group G in [0,22), strip s in [0,11) -> emission rows r0..r0+7
// (r0 = 2+8s). PASS 0: plain local-max -> M0. PASS 1/2: inline dilation of the
// previous mask via a 2-row-lookahead ring (mask rows run 2 ahead of score rows,
// which run 2 ahead of emission). PASS 1 writes cumulative mask M1 = M0|new.
// PASS 2 emits candidates (and histograms them inline).
template <int PASS>
__device__ __forceinline__ void score_pass(
    int u, int x0, int y0, const float* __restrict__ S,
    const uint32_t* __restrict__ MIN_, uint32_t* __restrict__ MOUT,
    uint64_t* list, uint32_t* cnt_loc, uint64_t* cand, uint32_t* cand_count,
    uint32_t* __restrict__ ghist, int b) {
  const int G = u % NG, s = u / NG;
  const int r0 = 2 + 8 * s;
  const int gx0 = x0 - 12 + 4 * G;
  uint32_t colm = 0;
#pragma unroll
  for (int j = 0; j < 4; ++j)
    if ((unsigned)(gx0 + j) < (unsigned)W) colm |= 1u << j;

  // 16-col mask window starting at p2 = 4G-6 (covers 5-wide OR for 12 score cols)
  const int p2 = 4 * G - 6;
  const int pw2 = (p2 < 0) ? 0 : (p2 >> 5);
  const int psh2 = (p2 < 0) ? 0 : (p2 & 31);
  const int pls2 = (p2 < 0) ? -p2 : 0;

  float4 hw[5], cw[5];
  uint32_t snr[5], mor[5], cnb[5];
  constexpr int NK = (PASS == 0) ? 12 : 16;
#pragma unroll
  for (int k = 0; k < NK; ++k) {
    if (PASS != 0) {
      // mask row mr = r0-4+k; horizontal 5-OR (bit i <-> supp col 4G-4+i) +
      // center nibble (cols 4G..4G+3) for the cumulative mask.
      const int mr = r0 - 4 + k;
      uint32_t morrow = 0, cnib = 0;
      if ((unsigned)mr < (unsigned)RROWS) {
        const uint32_t* srow = MIN_ + mr * MW4;
        uint64_t X = (uint64_t)srow[pw2] | ((uint64_t)srow[pw2 + 1] << 32);
        uint64_t win = pls2 ? (X << pls2) : (X >> psh2);
        uint64_t t5 = win | (win >> 1) | (win >> 2) | (win >> 3) | (win >> 4);
        morrow = (uint32_t)t5 & 0xFFFu;
        cnib = (uint32_t)(win >> 6) & 0xFu;
      }
      mor[k % 5] = morrow;
      cnb[k % 5] = cnib;
    }
    const int ks = (PASS == 0) ? k : k - 4;
    if (ks >= 0) {
      // score row sr = r0-2+ks; its 2D supp = OR of mor ring (mask rows sr-2..sr+2)
      const int sr = r0 - 2 + ks;
      uint32_t supp = 0;
      if (PASS != 0) supp = mor[0] | mor[1] | mor[2] | mor[3] | mor[4];
      const float* rowp = S + sr * STR + 4 * G;
      float4 d = ld4(rowp);
      float4 a = (G > 0) ? ld4(rowp - 4) : d;  // garbage-only cols, safe
      float4 e = (G < NG - 1) ? ld4(rowp + 4) : d;
      if (PASS != 0) {
        if (supp & 0x001u) a.x = 0.f;
        if (supp & 0x002u) a.y = 0.f;
        if (supp & 0x004u) a.z = 0.f;
        if (supp & 0x008u) a.w = 0.f;
        if (supp & 0x010u) d.x = 0.f;
        if (supp & 0x020u) d.y = 0.f;
        if (supp & 0x040u) d.z = 0.f;
        if (supp & 0x080u) d.w = 0.f;
        if (supp & 0x100u) e.x = 0.f;
        if (supp & 0x200u) e.y = 0.f;
        if (supp & 0x400u) e.z = 0.f;
        if (supp & 0x800u) e.w = 0.f;
      }
      float4 hm;
      hm.x = max5(a.z, a.w, d.x, d.y, d.z);
      hm.y = max5(a.w, d.x, d.y, d.z, d.w);
      hm.z = max5(d.x, d.y, d.z, d.w, e.x);
      hm.w = max5(d.y, d.z, d.w, e.x, e.y);
      hw[ks % 5] = hm;
      cw[ks % 5] = d;
      snr[ks % 5] = (supp >> 4) & 0xFu;
      if (ks >= 4) {
        const int rq = r0 - 4 + ks;  // emission row
        const int gy = y0 - 12 + rq;
        float4 vm;
        vm.x = max5(hw[0].x, hw[1].x, hw[2].x, hw[3].x, hw[4].x);
        vm.y = max5(hw[0].y, hw[1].y, hw[2].y, hw[3].y, hw[4].y);
        vm.z = max5(hw[0].z, hw[1].z, hw[2].z, hw[3].z, hw[4].z);
        vm.w = max5(hw[0].w, hw[1].w, hw[2].w, hw[3].w, hw[4].w);
        float4 c = cw[(ks + 3) % 5];  // center (masked for PASS 1/2)
        uint32_t nm = (uint32_t)(c.x == vm.x) | ((uint32_t)(c.y == vm.y) << 1) |
                      ((uint32_t)(c.z == vm.z) << 2) | ((uint32_t)(c.w == vm.w) << 3);
        nm &= ((unsigned)gy < (unsigned)H) ? colm : 0u;
        const int widx = rq * MW4 + (G >> 3);
        const int shift = 4 * (G & 7);
        if (PASS == 0) {
          if (nm) atomicOr(&MOUT[widx], nm << shift);
        } else if (PASS == 1) {
          // cumulative mask after iter1: M0 center nibble | (new & ~supp_center)
          uint32_t fin = cnb[ks % 5] | (nm & ~snr[(ks + 3) % 5]);
          if (fin) atomicOr(&MOUT[widx], fin << shift);
        } else {
          uint32_t fin = cnb[ks % 5] | (nm & ~snr[(ks + 3) % 5]);
          if (fin && G >= 3 && G < 19 && rq >= 12 && rq < 76 && gy >= 2 && gy < H - 2) {
#pragma unroll
            for (int j = 0; j < 4; ++j) {
              if ((fin >> j) & 1u) {
                int gx = gx0 + j;
                if (gx >= 2 && gx < W - 2) {
                  float sval = S[rq * STR + 4 * G + j];  // original (unmasked) score
                  if (sval > 0.0f) {
                    uint32_t bits = __float_as_uint(sval);
                    atomicAdd(&ghist[(size_t)b * HIST_N + (bits >> 15)], 1u);  // inline hist
                    uint32_t flat = (uint32_t)(gy * W + gx);
                    uint64_t key = ((uint64_t)bits << 32) | (uint64_t)(0xFFFFFFFFu - flat);
                    uint32_t pos = atomicAdd(cnt_loc, 1u);
                    if (pos < (uint32_t)LIST_CAP) {
                      list[pos] = key;
                    } else {  // tie overflow: direct global append (rare)
                      uint32_t pp = atomicAdd(&cand_count[b], 1u);
                      if (pp < (uint32_t)CAND_CAP) cand[(size_t)b * CAND_CAP + pp] = key;
                    }
                  }
                }
              }
            }
          }
        }
      }
    }
  }
}

// ---------------- fused 3-pass NMS + candidate emit + inline histogram ---------------
__global__ void __launch_bounds__(256, 4) k_nms(const float* __restrict__ scores,
                                                uint64_t* __restrict__ cand,
                                                uint32_t* __restrict__ cand_count,
                                                uint32_t* __restrict__ ghist) {
  __shared__ float S[RROWS * STR];
  __shared__ uint32_t M0s[RROWS * MW4];
  __shared__ uint32_t M1s[RROWS * MW4];
  __shared__ uint64_t list[LIST_CAP];
  __shared__ uint32_t cnt_loc, base_g;
  const int b = blockIdx.z;
  const int x0 = blockIdx.x * 64, y0 = blockIdx.y * 64;
  const int tid = threadIdx.x;
  const float* img = scores + (size_t)b * H * W;
  if (tid == 0) cnt_loc = 0;

  for (int u = tid; u < RROWS * NG; u += 256) {
    int r = u / NG, G = u % NG;
    int gy = y0 - 12 + r, gx = x0 - 12 + 4 * G;
    float4 v;
    if ((unsigned)gy < (unsigned)H && (unsigned)gx < (unsigned)W)
      v = ld4(img + (size_t)gy * W + gx);
    else
      v = make_float4(-INFINITY, -INFINITY, -INFINITY, -INFINITY);
    *reinterpret_cast<float4*>(&S[r * STR + 4 * G]) = v;
  }
  for (int i = tid; i < RROWS * MW4; i += 256) {
    M0s[i] = 0;
    M1s[i] = 0;
  }
  __syncthreads();
  if (tid < NUNIT)
    score_pass<0>(tid, x0, y0, S, nullptr, M0s, nullptr, nullptr, nullptr, nullptr,
                  nullptr, b);
  __syncthreads();
  if (tid < NUNIT)
    score_pass<1>(tid, x0, y0, S, M0s, M1s, nullptr, nullptr, nullptr, nullptr,
                  nullptr, b);
  __syncthreads();
  if (tid < NUNIT)
    score_pass<2>(tid, x0, y0, S, M1s, nullptr, list, &cnt_loc, cand, cand_count,
                  ghist, b);
  __syncthreads();
  uint32_t nblk = cnt_loc;
  uint32_t nmain = nblk < (uint32_t)LIST_CAP ? nblk : (uint32_t)LIST_CAP;
  if (tid == 0) base_g = atomicAdd(&cand_count[b], nmain);
  __syncthreads();
  uint32_t bg = base_g;
  for (uint32_t i = tid; i < nmain; i += 256) {
    uint32_t pp = bg + i;
    if (pp < (uint32_t)CAND_CAP) cand[(size_t)b * CAND_CAP + pp] = list[i];
  }
}

// ---------------- find threshold bucket (chunk sums fused in) ------------------------
// One block per batch: thread t sums buckets [32t,32t+32) -> LDS suffix scan ->
// crossing thread rescans its 32 buckets for the exact threshold bucket.
__global__ void __launch_bounds__(1024) k_findthr(const uint32_t* __restrict__ ghist,
                                                  uint64_t* __restrict__ thr_key) {
  __shared__ uint32_t h[1024];
  const int b = blockIdx.x, t = threadIdx.x;
  const uint32_t* gh = ghist + (size_t)b * HIST_N + t * 32;
  uint32_t s = 0;
#pragma unroll
  for (int j = 0; j < 8; ++j) {
    uint4 v = *reinterpret_cast<const uint4*>(gh + 4 * j);
    s += v.x + v.y + v.z + v.w;
  }
  h[t] = s;
  __syncthreads();
  for (int d = 1; d < 1024; d <<= 1) {
    uint32_t v = (t + d < 1024) ? h[t + d] : 0u;
    __syncthreads();
    h[t] += v;
    __syncthreads();
  }
  uint32_t cum = h[t];                        // count of keys in buckets >= 32t
  uint32_t nxt = (t < 1023) ? h[t + 1] : 0u;  // count of keys in buckets >= 32(t+1)
  if (t == 0 && cum < (uint32_t)TOPK) thr_key[b] = 0ull;  // select all
  if (cum >= (uint32_t)TOPK && nxt < (uint32_t)TOPK) {
    uint32_t run = nxt;
    int thrb = t * 32;
    for (int j = 31; j >= 0; --j) {
      run += gh[j];
      if (run >= (uint32_t)TOPK) {
        thrb = t * 32 + j;
        break;
      }
    }
    thr_key[b] = (uint64_t)thrb << 47;
  }
}

// ---------------- compact ------------------------------------------------------------
__global__ void __launch_bounds__(1024) k_compact(const uint64_t* __restrict__ cand,
                                                  const uint32_t* __restrict__ cand_count,
                                                  const uint64_t* __restrict__ thr_key,
                                                  uint64_t* __restrict__ sel,
                                                  uint32_t* __restrict__ sel_count) {
  __shared__ uint64_t list[1024];
  __shared__ uint32_t cnt_loc;
  __shared__ uint32_t base_g;
  const int b = blockIdx.y;
  uint32_t n = cand_count[b];
  if (n > (uint32_t)CAND_CAP) n = CAND_CAP;
  const int tid = threadIdx.x;
  if (tid == 0) cnt_loc = 0;
  __syncthreads();
  uint32_t i = blockIdx.x * 1024 + tid;
  if (i < n) {
    uint64_t key = cand[(size_t)b * CAND_CAP + i];
    if (key >= thr_key[b]) {
      uint32_t pos = atomicAdd(&cnt_loc, 1u);
      list[pos] = key;
    }
  }
  __syncthreads();
  uint32_t nblk = cnt_loc;
  if (tid == 0 && nblk > 0) base_g = atomicAdd(&sel_count[b], nblk);
  __syncthreads();
  if (nblk > 0 && (uint32_t)tid < nblk) {
    uint32_t pp = base_g + tid;
    if (pp < (uint32_t)SEL_CAP) sel[(size_t)b * SEL_CAP + pp] = list[tid];
  }
}

// ---------------- full rank + scatter in one kernel ----------------------------------
// rank[me] = #{keys > me} over all n selected keys (keys distinct => permutation =>
// exact JAX top_k order). Chunks looped in-block; final rank scatters directly.
__global__ void __launch_bounds__(256) k_rank(const uint64_t* __restrict__ sel,
                                              const uint32_t* __restrict__ sel_count,
                                              uint64_t* __restrict__ topk) {
  __shared__ uint64_t keys[RK_CH];  // 8 KiB
  const int b = blockIdx.y;
  uint32_t n = sel_count[b];
  if (n > (uint32_t)SEL_CAP) n = SEL_CAP;
  if (blockIdx.x * 256u >= n) return;  // uniform per block
  const uint64_t* sb = sel + (size_t)b * SEL_CAP;
  const uint32_t me = blockIdx.x * 256u + threadIdx.x;
  const uint64_t kme = (me < n) ? sb[me] : 0ull;
  uint32_t rank = 0;
  for (uint32_t c0 = 0; c0 < n; c0 += RK_CH) {
    uint32_t clen = n - c0;
    if (clen > (uint32_t)RK_CH) clen = RK_CH;
    __syncthreads();
    for (uint32_t i = threadIdx.x; i < clen; i += 256) keys[i] = sb[c0 + i];
    __syncthreads();
    uint32_t i = 0;
    for (; i + 8 <= clen; i += 8) {
      rank += (keys[i] > kme);
      rank += (keys[i + 1] > kme);
      rank += (keys[i + 2] > kme);
      rank += (keys[i + 3] > kme);
      rank += (keys[i + 4] > kme);
      rank += (keys[i + 5] > kme);
      rank += (keys[i + 6] > kme);
      rank += (keys[i + 7] > kme);
    }
    for (; i < clen; ++i) rank += (keys[i] > kme);
  }
  if (me < n && rank < (uint32_t)TOPK) topk[(size_t)b * TOPK + rank] = kme;
}

// ---------------- refinement: 8 lanes per keypoint -----------------------------------
__global__ void __launch_bounds__(256) k_refine(const float* __restrict__ scores,
                                                const uint64_t* __restrict__ topk,
                                                float* __restrict__ out) {
  int gid = blockIdx.x * 256 + threadIdx.x;
  int kp = gid >> 3, ln = gid & 7;
  const int b = kp / TOPK;
  const int k = kp % TOPK;
  uint64_t key = topk[(size_t)b * TOPK + k];
  uint32_t flat = 0xFFFFFFFFu - (uint32_t)(key & 0xFFFFFFFFull);
  if (flat >= (uint32_t)(H * W)) flat = 0;  // pad-key guard
  const int ix = (int)(flat % W);
  const int iy = (int)(flat / W);
  const float* img = scores + (size_t)b * H * W;

  const int nt = (ln == 0) ? 4 : 3;
  float v[4];
  float mymax = -INFINITY;
#pragma unroll
  for (int i = 0; i < 4; ++i) {
    if (i < nt) {
      int t = ln + 8 * i;
      int y = iy + t / 5 - 2, x = ix + t % 5 - 2;
      float val = ((unsigned)x < (unsigned)W && (unsigned)y < (unsigned)H)
                      ? img[(size_t)y * W + x] : 0.0f;
      v[i] = val;
      mymax = fmaxf(mymax, val);
    }
  }
#pragma unroll
  for (int m = 1; m < 8; m <<= 1) mymax = fmaxf(mymax, __shfl_xor(mymax, m));
  float e[4];
  float sum = 0.f, sx = 0.f, sy = 0.f;
#pragma unroll
  for (int i = 0; i < 4; ++i) {
    if (i < nt) {
      int t = ln + 8 * i;
      float ev = expf((v[i] - mymax) / 0.1f);
      e[i] = ev;
      sum += ev;
      sx += ev * (float)(t % 5 - 2);
      sy += ev * (float)(t / 5 - 2);
    }
  }
#pragma unroll
  for (int m = 1; m < 8; m <<= 1) {
    sum += __shfl_xor(sum, m);
    sx += __shfl_xor(sx, m);
    sy += __shfl_xor(sy, m);
  }
  float rx = sx / sum, ry = sy / sum;
  float dsp = 0.f;
#pragma unroll
  for (int i = 0; i < 4; ++i) {
    if (i < nt) {
      int t = ln + 8 * i;
      float dx = ((float)(t % 5 - 2) - rx) * 0.5f;
      float dy = ((float)(t / 5 - 2) - ry) * 0.5f;
      dsp += e[i] * (dx * dx + dy * dy);
    }
  }
#pragma unroll
  for (int m = 1; m < 8; m <<= 1) dsp += __shfl_xor(dsp, m);
  if (ln != 0) return;
  dsp /= sum;
  float kx = ((float)ix + rx) / 1023.0f * 2.0f - 1.0f;
  float ky = ((float)iy + ry) / 1023.0f * 2.0f - 1.0f;
  float px = (kx + 1.0f) * 0.5f * 1023.0f;
  float py = (ky + 1.0f) * 0.5f * 1023.0f;
  float x0f = floorf(px), y0f = floorf(py);
  float wx1 = px - x0f, wx0 = 1.0f - wx1;
  float wy1 = py - y0f, wy0 = 1.0f - wy1;
  int x0 = (int)x0f, y0 = (int)y0f;
  float sc = 0.0f;
  {
    int xs[2] = {x0, x0 + 1};
    int ys[2] = {y0, y0 + 1};
    float wxs[2] = {wx0, wx1};
    float wys[2] = {wy0, wy1};
#pragma unroll
    for (int yy = 0; yy < 2; ++yy)
#pragma unroll
      for (int xx = 0; xx < 2; ++xx) {
        int xi = xs[xx], yi = ys[yy];
        bool valid = (xi >= 0 && xi < W && yi >= 0 && yi < H);
        int xc = min(max(xi, 0), W - 1);
        int yc = min(max(yi, 0), H - 1);
        float vv = valid ? img[(size_t)yc * W + xc] : 0.0f;
        sc += vv * (wxs[xx] * wys[yy]);
      }
  }
  out[((size_t)b * TOPK + k) * 2 + 0] = kx;
  out[((size_t)b * TOPK + k) * 2 + 1] = ky;
  out[(size_t)B * TOPK * 2 + (size_t)b * TOPK + k] = sc;
  out[(size_t)B * TOPK * 3 + (size_t)b * TOPK + k] = dsp;
}

}  // namespace

extern "C" void kernel_launch(void* const* d_in, const int* in_sizes, int n_in,
                              void* d_out, int out_size, void* d_ws, size_t ws_size,
                              hipStream_t stream) {
  const float* scores = (const float*)d_in[0];
  float* out = (float*)d_out;
  char* ws = (char*)d_ws;

  uint32_t* cnt = (uint32_t*)(ws + OFF_CNT);
  uint32_t* cand_count = cnt;                    // [B]
  uint32_t* sel_count  = cnt + 8;                // [B]
  uint64_t* thr_key    = (uint64_t*)(cnt + 16);  // [B]
  uint32_t* ghist = (uint32_t*)(ws + OFF_GHIST);
  uint64_t* sel  = (uint64_t*)(ws + OFF_SEL);
  uint64_t* topk = (uint64_t*)(ws + OFF_TOPK);
  uint64_t* cand = (uint64_t*)(ws + OFF_CAND);

  hipMemsetAsync(ws + OFF_CNT, 0, MEMSET_BYTES, stream);

  k_nms<<<dim3(W / 64, H / 64, B), 256, 0, stream>>>(scores, cand, cand_count, ghist);
  k_findthr<<<B, 1024, 0, stream>>>(ghist, thr_key);
  k_compact<<<dim3(CAND_CAP / 1024, B), 1024, 0, stream>>>(cand, cand_count, thr_key,
                                                           sel, sel_count);
  k_rank<<<dim3(SEL_CAP / 256, B), 256, 0, stream>>>(sel, sel_count, topk);
  k_refine<<<(B * TOPK * 8) / 256, 256, 0, stream>>>(scores, topk, out);
}

// Round 2
// 270.256 us; speedup vs baseline: 2.3320x; 2.3320x over previous
//
#include <hip/hip_runtime.h>
#include <stdint.h>

namespace {

constexpr int B = 8;
constexpr int H = 1024;
constexpr int W = 1024;
constexpr int TOPK = 4096;
constexpr int CAND_CAP = 131072;  // per batch
constexpr int SEL_CAP = 16384;    // per batch
constexpr int LIST_CAP = 320;     // per 64x64 tile
constexpr int HIST_N = 32768;     // 17-bit key prefix = score_bits>>15

// fused-NMS tile: 64x64 interior, radius-12 staged halo.
// Validity chain (3 fused stages): M0 mask valid rows [2,89]/cols [2,86);
// M1 (cumulative after iter1) valid rows [4,87]/cols [4,84); final emission
// valid rows [6,85]/cols [6,82) => interior rows/cols 12..75 fully covered.
constexpr int RROWS = 92;   // staged score rows
constexpr int NG = 22;      // float4 col-groups (88 cols)
constexpr int STR = 88;     // score row stride (floats)
constexpr int MW4 = 4;      // bitpacked mask words per row (96+ bits; word 3 = zero pad)
constexpr int NSTRIP = 11;  // 11 strips x 8 output rows = rows 2..89
constexpr int NUNIT = NG * NSTRIP;  // 242 <= 256

constexpr int RK_CH = 1024;  // rank kernel: keys staged in LDS per chunk

// workspace layout (bytes)
constexpr size_t OFF_CNT   = 0;                                    // 4 KiB
constexpr size_t OFF_GHIST = 4096;                                 // B*HIST_N*4 = 1 MiB
constexpr size_t OFF_RANK  = OFF_GHIST + (size_t)B * HIST_N * 4;   // (region unused now)
constexpr size_t OFF_SEL   = OFF_RANK + (size_t)B * SEL_CAP * 4;
constexpr size_t OFF_TOPK  = OFF_SEL + (size_t)B * SEL_CAP * 8;
constexpr size_t OFF_CAND  = OFF_TOPK + (size_t)B * TOPK * 8;
constexpr size_t MEMSET_BYTES = OFF_RANK;  // cnt + ghist only

__device__ __forceinline__ float max5(float a, float b, float c, float d, float e) {
  return fmaxf(fmaxf(fmaxf(a, b), fmaxf(c, d)), e);
}
__device__ __forceinline__ float4 ld4(const float* p) {
  return *reinterpret_cast<const float4*>(p);
}

// One unit: col-group G in [0,22), strip s in [0,11) -> emission rows r0..r0+7
// (r0 = 2+8s). PASS 0: plain local-max -> M0. PASS 1/2: inline dilation of the
// previous mask via a 2-row-lookahead ring (mask rows run 2 ahead of score rows,
// which run 2 ahead of emission). PASS 1 writes cumulative mask M1 = M0|new.
// PASS 2 emits candidates into the LDS list (histogram happens in the tail,
// wave-aggregated; a per-candidate global atomic here was a 6x regression:
// hot-bucket contention, 10% VALUBusy, +17 MB write-back).
template <int PASS>
__device__ __forceinline__ void score_pass(
    int u, int x0, int y0, const float* __restrict__ S,
    const uint32_t* __restrict__ MIN_, uint32_t* __restrict__ MOUT,
    uint64_t* list, uint32_t* cnt_loc, uint64_t* cand, uint32_t* cand_count,
    uint32_t* __restrict__ ghist, int b) {
  const int G = u % NG, s = u / NG;
  const int r0 = 2 + 8 * s;
  const int gx0 = x0 - 12 + 4 * G;
  uint32_t colm = 0;
#pragma unroll
  for (int j = 0; j < 4; ++j)
    if ((unsigned)(gx0 + j) < (unsigned)W) colm |= 1u << j;

  // 16-col mask window starting at p2 = 4G-6 (covers 5-wide OR for 12 score cols)
  const int p2 = 4 * G - 6;
  const int pw2 = (p2 < 0) ? 0 : (p2 >> 5);
  const int psh2 = (p2 < 0) ? 0 : (p2 & 31);
  const int pls2 = (p2 < 0) ? -p2 : 0;

  float4 hw[5], cw[5];
  uint32_t snr[5], mor[5], cnb[5];
  constexpr int NK = (PASS == 0) ? 12 : 16;
#pragma unroll
  for (int k = 0; k < NK; ++k) {
    if (PASS != 0) {
      // mask row mr = r0-4+k; horizontal 5-OR (bit i <-> supp col 4G-4+i) +
      // center nibble (cols 4G..4G+3) for the cumulative mask.
      const int mr = r0 - 4 + k;
      uint32_t morrow = 0, cnib = 0;
      if ((unsigned)mr < (unsigned)RROWS) {
        const uint32_t* srow = MIN_ + mr * MW4;
        uint64_t X = (uint64_t)srow[pw2] | ((uint64_t)srow[pw2 + 1] << 32);
        uint64_t win = pls2 ? (X << pls2) : (X >> psh2);
        uint64_t t5 = win | (win >> 1) | (win >> 2) | (win >> 3) | (win >> 4);
        morrow = (uint32_t)t5 & 0xFFFu;
        cnib = (uint32_t)(win >> 6) & 0xFu;
      }
      mor[k % 5] = morrow;
      cnb[k % 5] = cnib;
    }
    const int ks = (PASS == 0) ? k : k - 4;
    if (ks >= 0) {
      // score row sr = r0-2+ks; its 2D supp = OR of mor ring (mask rows sr-2..sr+2)
      const int sr = r0 - 2 + ks;
      uint32_t supp = 0;
      if (PASS != 0) supp = mor[0] | mor[1] | mor[2] | mor[3] | mor[4];
      const float* rowp = S + sr * STR + 4 * G;
      float4 d = ld4(rowp);
      float4 a = (G > 0) ? ld4(rowp - 4) : d;  // garbage-only cols, safe
      float4 e = (G < NG - 1) ? ld4(rowp + 4) : d;
      if (PASS != 0) {
        if (supp & 0x001u) a.x = 0.f;
        if (supp & 0x002u) a.y = 0.f;
        if (supp & 0x004u) a.z = 0.f;
        if (supp & 0x008u) a.w = 0.f;
        if (supp & 0x010u) d.x = 0.f;
        if (supp & 0x020u) d.y = 0.f;
        if (supp & 0x040u) d.z = 0.f;
        if (supp & 0x080u) d.w = 0.f;
        if (supp & 0x100u) e.x = 0.f;
        if (supp & 0x200u) e.y = 0.f;
        if (supp & 0x400u) e.z = 0.f;
        if (supp & 0x800u) e.w = 0.f;
      }
      float4 hm;
      hm.x = max5(a.z, a.w, d.x, d.y, d.z);
      hm.y = max5(a.w, d.x, d.y, d.z, d.w);
      hm.z = max5(d.x, d.y, d.z, d.w, e.x);
      hm.w = max5(d.y, d.z, d.w, e.x, e.y);
      hw[ks % 5] = hm;
      cw[ks % 5] = d;
      snr[ks % 5] = (supp >> 4) & 0xFu;
      if (ks >= 4) {
        const int rq = r0 - 4 + ks;  // emission row
        const int gy = y0 - 12 + rq;
        float4 vm;
        vm.x = max5(hw[0].x, hw[1].x, hw[2].x, hw[3].x, hw[4].x);
        vm.y = max5(hw[0].y, hw[1].y, hw[2].y, hw[3].y, hw[4].y);
        vm.z = max5(hw[0].z, hw[1].z, hw[2].z, hw[3].z, hw[4].z);
        vm.w = max5(hw[0].w, hw[1].w, hw[2].w, hw[3].w, hw[4].w);
        float4 c = cw[(ks + 3) % 5];  // center (masked for PASS 1/2)
        uint32_t nm = (uint32_t)(c.x == vm.x) | ((uint32_t)(c.y == vm.y) << 1) |
                      ((uint32_t)(c.z == vm.z) << 2) | ((uint32_t)(c.w == vm.w) << 3);
        nm &= ((unsigned)gy < (unsigned)H) ? colm : 0u;
        const int widx = rq * MW4 + (G >> 3);
        const int shift = 4 * (G & 7);
        if (PASS == 0) {
          if (nm) atomicOr(&MOUT[widx], nm << shift);
        } else if (PASS == 1) {
          // cumulative mask after iter1: M0 center nibble | (new & ~supp_center)
          uint32_t fin = cnb[ks % 5] | (nm & ~snr[(ks + 3) % 5]);
          if (fin) atomicOr(&MOUT[widx], fin << shift);
        } else {
          uint32_t fin = cnb[ks % 5] | (nm & ~snr[(ks + 3) % 5]);
          if (fin && G >= 3 && G < 19 && rq >= 12 && rq < 76 && gy >= 2 && gy < H - 2) {
#pragma unroll
            for (int j = 0; j < 4; ++j) {
              if ((fin >> j) & 1u) {
                int gx = gx0 + j;
                if (gx >= 2 && gx < W - 2) {
                  float sval = S[rq * STR + 4 * G + j];  // original (unmasked) score
                  if (sval > 0.0f) {
                    uint32_t bits = __float_as_uint(sval);
                    uint32_t flat = (uint32_t)(gy * W + gx);
                    uint64_t key = ((uint64_t)bits << 32) | (uint64_t)(0xFFFFFFFFu - flat);
                    uint32_t pos = atomicAdd(cnt_loc, 1u);
                    if (pos < (uint32_t)LIST_CAP) {
                      list[pos] = key;
                    } else {  // tie overflow: direct global append + hist (rare)
                      uint32_t pp = atomicAdd(&cand_count[b], 1u);
                      if (pp < (uint32_t)CAND_CAP) cand[(size_t)b * CAND_CAP + pp] = key;
                      atomicAdd(&ghist[(size_t)b * HIST_N + (bits >> 15)], 1u);
                    }
                  }
                }
              }
            }
          }
        }
      }
    }
  }
}

// ---------------- fused 3-pass NMS + candidate emit + wave-aggregated hist -----------
__global__ void __launch_bounds__(256, 4) k_nms(const float* __restrict__ scores,
                                                uint64_t* __restrict__ cand,
                                                uint32_t* __restrict__ cand_count,
                                                uint32_t* __restrict__ ghist) {
  __shared__ float S[RROWS * STR];
  __shared__ uint32_t M0s[RROWS * MW4];
  __shared__ uint32_t M1s[RROWS * MW4];
  __shared__ uint64_t list[LIST_CAP];
  __shared__ uint32_t cnt_loc, base_g;
  const int b = blockIdx.z;
  const int x0 = blockIdx.x * 64, y0 = blockIdx.y * 64;
  const int tid = threadIdx.x;
  const float* img = scores + (size_t)b * H * W;
  if (tid == 0) cnt_loc = 0;

  for (int u = tid; u < RROWS * NG; u += 256) {
    int r = u / NG, G = u % NG;
    int gy = y0 - 12 + r, gx = x0 - 12 + 4 * G;
    float4 v;
    if ((unsigned)gy < (unsigned)H && (unsigned)gx < (unsigned)W)
      v = ld4(img + (size_t)gy * W + gx);
    else
      v = make_float4(-INFINITY, -INFINITY, -INFINITY, -INFINITY);
    *reinterpret_cast<float4*>(&S[r * STR + 4 * G]) = v;
  }
  for (int i = tid; i < RROWS * MW4; i += 256) {
    M0s[i] = 0;
    M1s[i] = 0;
  }
  __syncthreads();
  if (tid < NUNIT)
    score_pass<0>(tid, x0, y0, S, nullptr, M0s, nullptr, nullptr, nullptr, nullptr,
                  nullptr, b);
  __syncthreads();
  if (tid < NUNIT)
    score_pass<1>(tid, x0, y0, S, M0s, M1s, nullptr, nullptr, nullptr, nullptr,
                  nullptr, b);
  __syncthreads();
  if (tid < NUNIT)
    score_pass<2>(tid, x0, y0, S, M1s, nullptr, list, &cnt_loc, cand, cand_count,
                  ghist, b);
  __syncthreads();
  uint32_t nblk = cnt_loc;
  uint32_t nmain = nblk < (uint32_t)LIST_CAP ? nblk : (uint32_t)LIST_CAP;
  if (tid == 0) base_g = atomicAdd(&cand_count[b], nmain);
  __syncthreads();
  uint32_t bg = base_g;
  uint32_t* gh = ghist + (size_t)b * HIST_N;
  const int lane = tid & 63;
  // write-out + wave match-any histogram (one atomic per (wave,bucket) group)
  for (uint32_t i = tid;; i += 256) {
    bool valid = i < nmain;
    uint64_t act = __ballot(valid);
    if (!act) break;
    uint32_t bkt = 0;
    if (valid) {
      uint64_t key = list[i];
      uint32_t pp = bg + i;
      if (pp < (uint32_t)CAND_CAP) cand[(size_t)b * CAND_CAP + pp] = key;
      bkt = (uint32_t)(key >> 47);  // = score_bits >> 15, < 32768
    }
    uint64_t peers = act;
#pragma unroll
    for (int bit = 0; bit < 15; ++bit) {
      uint64_t bb = __ballot((bkt >> bit) & 1u);
      peers &= ((bkt >> bit) & 1u) ? bb : ~bb;
    }
    if (valid && (__ffsll((unsigned long long)peers) - 1) == lane)
      atomicAdd(&gh[bkt], (uint32_t)__popcll((unsigned long long)peers));
  }
}

// ---------------- find threshold bucket (chunk sums fused in) ------------------------
// One block per batch: thread t sums buckets [32t,32t+32) -> LDS suffix scan ->
// crossing thread rescans its 32 buckets for the exact threshold bucket.
__global__ void __launch_bounds__(1024) k_findthr(const uint32_t* __restrict__ ghist,
                                                  uint64_t* __restrict__ thr_key) {
  __shared__ uint32_t h[1024];
  const int b = blockIdx.x, t = threadIdx.x;
  const uint32_t* gh = ghist + (size_t)b * HIST_N + t * 32;
  uint32_t s = 0;
#pragma unroll
  for (int j = 0; j < 8; ++j) {
    uint4 v = *reinterpret_cast<const uint4*>(gh + 4 * j);
    s += v.x + v.y + v.z + v.w;
  }
  h[t] = s;
  __syncthreads();
  for (int d = 1; d < 1024; d <<= 1) {
    uint32_t v = (t + d < 1024) ? h[t + d] : 0u;
    __syncthreads();
    h[t] += v;
    __syncthreads();
  }
  uint32_t cum = h[t];                        // count of keys in buckets >= 32t
  uint32_t nxt = (t < 1023) ? h[t + 1] : 0u;  // count of keys in buckets >= 32(t+1)
  if (t == 0 && cum < (uint32_t)TOPK) thr_key[b] = 0ull;  // select all
  if (cum >= (uint32_t)TOPK && nxt < (uint32_t)TOPK) {
    uint32_t run = nxt;
    int thrb = t * 32;
    for (int j = 31; j >= 0; --j) {
      run += gh[j];
      if (run >= (uint32_t)TOPK) {
        thrb = t * 32 + j;
        break;
      }
    }
    thr_key[b] = (uint64_t)thrb << 47;
  }
}

// ---------------- compact ------------------------------------------------------------
__global__ void __launch_bounds__(1024) k_compact(const uint64_t* __restrict__ cand,
                                                  const uint32_t* __restrict__ cand_count,
                                                  const uint64_t* __restrict__ thr_key,
                                                  uint64_t* __restrict__ sel,
                                                  uint32_t* __restrict__ sel_count) {
  __shared__ uint64_t list[1024];
  __shared__ uint32_t cnt_loc;
  __shared__ uint32_t base_g;
  const int b = blockIdx.y;
  uint32_t n = cand_count[b];
  if (n > (uint32_t)CAND_CAP) n = CAND_CAP;
  const int tid = threadIdx.x;
  if (tid == 0) cnt_loc = 0;
  __syncthreads();
  uint32_t i = blockIdx.x * 1024 + tid;
  if (i < n) {
    uint64_t key = cand[(size_t)b * CAND_CAP + i];
    if (key >= thr_key[b]) {
      uint32_t pos = atomicAdd(&cnt_loc, 1u);
      list[pos] = key;
    }
  }
  __syncthreads();
  uint32_t nblk = cnt_loc;
  if (tid == 0 && nblk > 0) base_g = atomicAdd(&sel_count[b], nblk);
  __syncthreads();
  if (nblk > 0 && (uint32_t)tid < nblk) {
    uint32_t pp = base_g + tid;
    if (pp < (uint32_t)SEL_CAP) sel[(size_t)b * SEL_CAP + pp] = list[tid];
  }
}

// ---------------- full rank + scatter in one kernel ----------------------------------
// rank[me] = #{keys > me} over all n selected keys (keys distinct => permutation =>
// exact JAX top_k order). Chunks looped in-block; final rank scatters directly.
__global__ void __launch_bounds__(256) k_rank(const uint64_t* __restrict__ sel,
                                              const uint32_t* __restrict__ sel_count,
                                              uint64_t* __restrict__ topk) {
  __shared__ uint64_t keys[RK_CH];  // 8 KiB
  const int b = blockIdx.y;
  uint32_t n = sel_count[b];
  if (n > (uint32_t)SEL_CAP) n = SEL_CAP;
  if (blockIdx.x * 256u >= n) return;  // uniform per block
  const uint64_t* sb = sel + (size_t)b * SEL_CAP;
  const uint32_t me = blockIdx.x * 256u + threadIdx.x;
  const uint64_t kme = (me < n) ? sb[me] : 0ull;
  uint32_t rank = 0;
  for (uint32_t c0 = 0; c0 < n; c0 += RK_CH) {
    uint32_t clen = n - c0;
    if (clen > (uint32_t)RK_CH) clen = RK_CH;
    __syncthreads();
    for (uint32_t i = threadIdx.x; i < clen; i += 256) keys[i] = sb[c0 + i];
    __syncthreads();
    uint32_t i = 0;
    for (; i + 8 <= clen; i += 8) {
      rank += (keys[i] > kme);
      rank += (keys[i + 1] > kme);
      rank += (keys[i + 2] > kme);
      rank += (keys[i + 3] > kme);
      rank += (keys[i + 4] > kme);
      rank += (keys[i + 5] > kme);
      rank += (keys[i + 6] > kme);
      rank += (keys[i + 7] > kme);
    }
    for (; i < clen; ++i) rank += (keys[i] > kme);
  }
  if (me < n && rank < (uint32_t)TOPK) topk[(size_t)b * TOPK + rank] = kme;
}

// ---------------- refinement: 8 lanes per keypoint -----------------------------------
__global__ void __launch_bounds__(256) k_refine(const float* __restrict__ scores,
                                                const uint64_t* __restrict__ topk,
                                                float* __restrict__ out) {
  int gid = blockIdx.x * 256 + threadIdx.x;
  int kp = gid >> 3, ln = gid & 7;
  const int b = kp / TOPK;
  const int k = kp % TOPK;
  uint64_t key = topk[(size_t)b * TOPK + k];
  uint32_t flat = 0xFFFFFFFFu - (uint32_t)(key & 0xFFFFFFFFull);
  if (flat >= (uint32_t)(H * W)) flat = 0;  // pad-key guard
  const int ix = (int)(flat % W);
  const int iy = (int)(flat / W);
  const float* img = scores + (size_t)b * H * W;

  const int nt = (ln == 0) ? 4 : 3;
  float v[4];
  float mymax = -INFINITY;
#pragma unroll
  for (int i = 0; i < 4; ++i) {
    if (i < nt) {
      int t = ln + 8 * i;
      int y = iy + t / 5 - 2, x = ix + t % 5 - 2;
      float val = ((unsigned)x < (unsigned)W && (unsigned)y < (unsigned)H)
                      ? img[(size_t)y * W + x] : 0.0f;
      v[i] = val;
      mymax = fmaxf(mymax, val);
    }
  }
#pragma unroll
  for (int m = 1; m < 8; m <<= 1) mymax = fmaxf(mymax, __shfl_xor(mymax, m));
  float e[4];
  float sum = 0.f, sx = 0.f, sy = 0.f;
#pragma unroll
  for (int i = 0; i < 4; ++i) {
    if (i < nt) {
      int t = ln + 8 * i;
      float ev = expf((v[i] - mymax) / 0.1f);
      e[i] = ev;
      sum += ev;
      sx += ev * (float)(t % 5 - 2);
      sy += ev * (float)(t / 5 - 2);
    }
  }
#pragma unroll
  for (int m = 1; m < 8; m <<= 1) {
    sum += __shfl_xor(sum, m);
    sx += __shfl_xor(sx, m);
    sy += __shfl_xor(sy, m);
  }
  float rx = sx / sum, ry = sy / sum;
  float dsp = 0.f;
#pragma unroll
  for (int i = 0; i < 4; ++i) {
    if (i < nt) {
      int t = ln + 8 * i;
      float dx = ((float)(t % 5 - 2) - rx) * 0.5f;
      float dy = ((float)(t / 5 - 2) - ry) * 0.5f;
      dsp += e[i] * (dx * dx + dy * dy);
    }
  }
#pragma unroll
  for (int m = 1; m < 8; m <<= 1) dsp += __shfl_xor(dsp, m);
  if (ln != 0) return;
  dsp /= sum;
  float kx = ((float)ix + rx) / 1023.0f * 2.0f - 1.0f;
  float ky = ((float)iy + ry) / 1023.0f * 2.0f - 1.0f;
  float px = (kx + 1.0f) * 0.5f * 1023.0f;
  float py = (ky + 1.0f) * 0.5f * 1023.0f;
  float x0f = floorf(px), y0f = floorf(py);
  float wx1 = px - x0f, wx0 = 1.0f - wx1;
  float wy1 = py - y0f, wy0 = 1.0f - wy1;
  int x0 = (int)x0f, y0 = (int)y0f;
  float sc = 0.0f;
  {
    int xs[2] = {x0, x0 + 1};
    int ys[2] = {y0, y0 + 1};
    float wxs[2] = {wx0, wx1};
    float wys[2] = {wy0, wy1};
#pragma unroll
    for (int yy = 0; yy < 2; ++yy)
#pragma unroll
      for (int xx = 0; xx < 2; ++xx) {
        int xi = xs[xx], yi = ys[yy];
        bool valid = (xi >= 0 && xi < W && yi >= 0 && yi < H);
        int xc = min(max(xi, 0), W - 1);
        int yc = min(max(yi, 0), H - 1);
        float vv = valid ? img[(size_t)yc * W + xc] : 0.0f;
        sc += vv * (wxs[xx] * wys[yy]);
      }
  }
  out[((size_t)b * TOPK + k) * 2 + 0] = kx;
  out[((size_t)b * TOPK + k) * 2 + 1] = ky;
  out[(size_t)B * TOPK * 2 + (size_t)b * TOPK + k] = sc;
  out[(size_t)B * TOPK * 3 + (size_t)b * TOPK + k] = dsp;
}

}  // namespace

extern "C" void kernel_launch(void* const* d_in, const int* in_sizes, int n_in,
                              void* d_out, int out_size, void* d_ws, size_t ws_size,
                              hipStream_t stream) {
  const float* scores = (const float*)d_in[0];
  float* out = (float*)d_out;
  char* ws = (char*)d_ws;

  uint32_t* cnt = (uint32_t*)(ws + OFF_CNT);
  uint32_t* cand_count = cnt;                    // [B]
  uint32_t* sel_count  = cnt + 8;                // [B]
  uint64_t* thr_key    = (uint64_t*)(cnt + 16);  // [B]
  uint32_t* ghist = (uint32_t*)(ws + OFF_GHIST);
  uint64_t* sel  = (uint64_t*)(ws + OFF_SEL);
  uint64_t* topk = (uint64_t*)(ws + OFF_TOPK);
  uint64_t* cand = (uint64_t*)(ws + OFF_CAND);

  hipMemsetAsync(ws + OFF_CNT, 0, MEMSET_BYTES, stream);

  k_nms<<<dim3(W / 64, H / 64, B), 256, 0, stream>>>(scores, cand, cand_count, ghist);
  k_findthr<<<B, 1024, 0, stream>>>(ghist, thr_key);
  k_compact<<<dim3(CAND_CAP / 1024, B), 1024, 0, stream>>>(cand, cand_count, thr_key,
                                                           sel, sel_count);
  k_rank<<<dim3(SEL_CAP / 256, B), 256, 0, stream>>>(sel, sel_count, topk);
  k_refine<<<(B * TOPK * 8) / 256, 256, 0, stream>>>(scores, topk, out);
}